// Round 18
// baseline (362.739 us; speedup 1.0000x reference)
//
#include <hip/hip_runtime.h>

#define HDIM 768
#define BM 32                 // rows per block (2 row-tiles)
#define NCHUNK 24             // K chunks of 32
#define CHALF 24576           // halves per Wt chunk (768 cols * 32 k)
#define A_STRIDE 1552         // bytes per A row in LDS (768*2 + 16 pad)

typedef _Float16 f16x8 __attribute__((ext_vector_type(8)));
typedef _Float16 f16x4 __attribute__((ext_vector_type(4)));
typedef _Float16 f16x2 __attribute__((ext_vector_type(2)));
typedef float f32x4 __attribute__((ext_vector_type(4)));

// ---- LDS layout (bytes), dynamic: 57984 -> 2 blocks/CU (8 waves/SIMD) ----
#define LDS_A     0            // A resident: [32][1552B] = 49664
#define LDS_BIAS  49664        // 768 f32
#define LDS_V     52736        // 768 f32
#define LDS_SRED  55808        // [16][32] f32 = 2048
#define LDS_E     57856        // 32 f32
#define LDS_TOTAL 57984

// ---- workspace layout (bytes) ----
#define WS_WT    0             // 768*768*2 = 1179648 (fp16 W, chunked [kc][col][32k], linear)
#define WS_Z     1179648       // 4 (+pad) [absorbs the benign tail B-prefetch OOB read]
#define WS_PART  1179712       // 4096*768*4 = 12582912
#define WS_PART2 13762624      // 32*768*4 = 98304
#define WS_NEED  (WS_PART2 + 98304)

__device__ __forceinline__ float tanh_fast(float z) {
    float e2 = __expf(2.0f * z);
    return 1.0f - 2.0f / (e2 + 1.0f);   // inf-safe at both extremes
}

__device__ __forceinline__ f16x8 cvt8(f32x4 x0, f32x4 x1) {
    f16x8 f;
    f[0] = (_Float16)x0[0]; f[1] = (_Float16)x0[1];
    f[2] = (_Float16)x0[2]; f[3] = (_Float16)x0[3];
    f[4] = (_Float16)x1[0]; f[5] = (_Float16)x1[1];
    f[6] = (_Float16)x1[2]; f[7] = (_Float16)x1[3];
    return f;
}

// ---------------- kernel 1: W -> fp16 chunks [kc][col][32k] (linear); zero Z + acc ----------------
__global__ __launch_bounds__(1024) void prep_kernel(
    const float* __restrict__ W, _Float16* __restrict__ Wt,
    float* __restrict__ Z, float* __restrict__ accbuf) {
    int idx = blockIdx.x * 1024 + threadIdx.x;      // 73728 groups: 768 c x 24 kc x 4 q
    if (idx < 73728) {
        int c  = idx / 96;
        int r  = idx - c * 96;
        int kc = r >> 2;
        int q  = r & 3;
        const float* src = W + c * HDIM + kc * 32 + q * 8;
        f16x8 v = cvt8(*(const f32x4*)src, *(const f32x4*)(src + 4));
        *(f16x8*)(Wt + (size_t)kc * CHALF + c * 32 + q * 8) = v;
    }
    if (idx < HDIM) accbuf[idx] = 0.0f;
    if (idx == 0) *Z = 0.0f;
}

// ---------------- kernel 2: fused GEMM + tanh + v-dot + exp + weighted sum ----------------
// r18 = r13 base (BM=32, 58KB LDS, 2 blocks/CU, 87% occ, passed) + 1-deep B register
// ping-pong prefetch (the one proven-positive schedule lever, r15) + __launch_bounds__
// (1024, 8) to FORCE the 64-unified-reg budget (r14 omitted the min-waves arg, the
// allocator picked a 4-wave budget and occupancy collapsed to 47%). Hypothesis under
// test: 2 blocks/CU provides the cross-block overlap (m114) that intra-block scheduling
// could not — wall moves from sum-of-pipes (~3450cy/chunk) toward max-of-pipes.
// Live set: acc 24 AGPR + B ping/pong 24 + A frags 8 + addr ~6 = 62 <= 64. WRITE_SIZE
// is the spill gate; OccupancyPercent >= 80 is the residency gate.
__global__ __launch_bounds__(1024, 8) void score_fused_kernel(
    const float* __restrict__ h, const _Float16* __restrict__ Wt,
    const float* __restrict__ bias, const float* __restrict__ vvec,
    float* __restrict__ part, float* __restrict__ accbuf,
    float* __restrict__ Z, int use_part) {

    extern __shared__ char smem[];
    float* bias_s = (float*)(smem + LDS_BIAS);
    float* v_s    = (float*)(smem + LDS_V);
    float* s_red  = (float*)(smem + LDS_SRED);
    float* e_lds  = (float*)(smem + LDS_E);

    const int tid  = threadIdx.x;
    const int wave = tid >> 6;       // = col-group 0..15 (48 cols each)
    const int lane = tid & 63;
    const int l15  = lane & 15;
    const int lhi  = lane >> 4;
    const int row0 = blockIdx.x * BM;

    if (tid < HDIM) { bias_s[tid] = bias[tid]; v_s[tid] = vvec[tid]; }

    // ---- prologue: stage A tile (32 x 768 fp32 -> fp16), coalesced, 6 f32x4/thread ----
    #pragma unroll
    for (int i = 0; i < 6; ++i) {
        int flat = i * 1024 + tid;          // 0..6143 = 32 rows x 192 f32x4
        int r  = flat / 192;
        int c4 = flat - r * 192;
        f32x4 x = __builtin_nontemporal_load(
            (const f32x4*)(h + (size_t)(row0 + r) * HDIM + c4 * 4));
        f16x4 v;
        v[0] = (_Float16)x[0]; v[1] = (_Float16)x[1];
        v[2] = (_Float16)x[2]; v[3] = (_Float16)x[3];
        *(f16x4*)(smem + LDS_A + r * A_STRIDE + c4 * 8) = v;
    }

    // B chunk-0 fragments into the ping set (L2-resident Wt)
    const _Float16* wtp = Wt + (wave * 48 + l15) * 32 + lhi * 8;
    f16x8 bA0 = *(const f16x8*)(wtp);
    f16x8 bA1 = *(const f16x8*)(wtp + 512);
    f16x8 bA2 = *(const f16x8*)(wtp + 1024);
    f16x8 bB0, bB1, bB2;

    __syncthreads();   // the only pre-epilogue barrier: A tile + bias/v visible

    f32x4 acc[2][3];
    #pragma unroll
    for (int rt = 0; rt < 2; ++rt)
        #pragma unroll
        for (int ct = 0; ct < 3; ++ct)
            acc[rt][ct] = (f32x4){0.f, 0.f, 0.f, 0.f};

    const char* aBase = smem + LDS_A + l15 * A_STRIDE + lhi * 16;

// compute chunk KC (ABSOLUTE index; pointers never advance) from B set C*; prefetch
// B(KC+1) into N*. A frags single-buffered (r17 proved double-buffering null).
// Tail: chunk 23 prefetches chunk 24 -> 48KB past Wt into Z/part (mapped, unused).
#define CHUNK(KC, C0, C1, C2, N0, N1, N2)                                                \
    {                                                                                    \
        const _Float16* wn = wtp + (size_t)((KC) + 1) * CHALF;                           \
        N0 = *(const f16x8*)(wn);                                                        \
        N1 = *(const f16x8*)(wn + 512);                                                  \
        N2 = *(const f16x8*)(wn + 1024);                                                 \
        const char* ab = aBase + (KC) * 64;                                              \
        f16x8 a0 = *(const f16x8*)(ab);                                                  \
        f16x8 a1 = *(const f16x8*)(ab + 16 * A_STRIDE);                                  \
        __builtin_amdgcn_s_setprio(1);                                                   \
        acc[0][0] = __builtin_amdgcn_mfma_f32_16x16x32_f16(a0, C0, acc[0][0], 0, 0, 0);  \
        acc[0][1] = __builtin_amdgcn_mfma_f32_16x16x32_f16(a0, C1, acc[0][1], 0, 0, 0);  \
        acc[0][2] = __builtin_amdgcn_mfma_f32_16x16x32_f16(a0, C2, acc[0][2], 0, 0, 0);  \
        acc[1][0] = __builtin_amdgcn_mfma_f32_16x16x32_f16(a1, C0, acc[1][0], 0, 0, 0);  \
        acc[1][1] = __builtin_amdgcn_mfma_f32_16x16x32_f16(a1, C1, acc[1][1], 0, 0, 0);  \
        acc[1][2] = __builtin_amdgcn_mfma_f32_16x16x32_f16(a1, C2, acc[1][2], 0, 0, 0);  \
        __builtin_amdgcn_s_setprio(0);                                                   \
    }

    #pragma unroll 1
    for (int k2 = 0; k2 < NCHUNK; k2 += 2) {
        CHUNK(k2,     bA0, bA1, bA2, bB0, bB1, bB2)
        CHUNK(k2 + 1, bB0, bB1, bB2, bA0, bA1, bA2)
    }
#undef CHUNK

    // ---- epilogue: per-wave col-partial scores ----
    float pr[2][4];
    #pragma unroll
    for (int rt = 0; rt < 2; ++rt)
        #pragma unroll
        for (int r = 0; r < 4; ++r) pr[rt][r] = 0.f;

    #pragma unroll
    for (int ct = 0; ct < 3; ++ct) {
        int col = wave * 48 + ct * 16 + l15;
        float bj = bias_s[col];
        float vj = v_s[col];
        #pragma unroll
        for (int rt = 0; rt < 2; ++rt)
            #pragma unroll
            for (int r = 0; r < 4; ++r)
                pr[rt][r] = fmaf(vj, tanh_fast(acc[rt][ct][r] + bj), pr[rt][r]);
    }
    #pragma unroll
    for (int rt = 0; rt < 2; ++rt)
        #pragma unroll
        for (int r = 0; r < 4; ++r) {
            float x = pr[rt][r];
            x += __shfl_xor(x, 1);
            x += __shfl_xor(x, 2);
            x += __shfl_xor(x, 4);
            x += __shfl_xor(x, 8);
            if (l15 == 0) s_red[wave * 32 + rt * 16 + lhi * 4 + r] = x;
        }
    __syncthreads();

    // rows: sum 16 col-group partials, exp, block Z
    if (tid < 32) {
        float s = 0.f;
        #pragma unroll
        for (int w = 0; w < 16; ++w) s += s_red[w * 32 + tid];
        float e = __expf(s);            // |s| <= ||v||_1 ~ 61: no overflow
        e_lds[tid] = e;
        float tot = e;
        tot += __shfl_xor(tot, 1);
        tot += __shfl_xor(tot, 2);
        tot += __shfl_xor(tot, 4);
        tot += __shfl_xor(tot, 8);
        tot += __shfl_xor(tot, 16);
        if (tid == 0) atomicAdd(Z, tot);
    }
    __syncthreads();

    // ---- fused weighted sum from resident A (h read from HBM exactly once), f16x2/lane ----
    if (tid < 384) {
        float s0 = 0.f, s1 = 0.f;
        #pragma unroll 8
        for (int i = 0; i < BM; ++i) {
            f16x2 a2 = *(const f16x2*)(smem + LDS_A + i * A_STRIDE + tid * 4);
            float e = e_lds[i];
            s0 = fmaf(e, (float)a2[0], s0);
            s1 = fmaf(e, (float)a2[1], s1);
        }
        if (use_part) {
            float* dst = part + (size_t)blockIdx.x * HDIM + tid * 2;
            dst[0] = s0; dst[1] = s1;
        } else {
            atomicAdd(accbuf + tid * 2, s0);
            atomicAdd(accbuf + tid * 2 + 1, s1);
        }
    }
}

// ---------------- finalize stage 1: sum 4096 parts in 32 groups of 128 ----------------
__global__ __launch_bounds__(128) void fin1_kernel(
    const float* __restrict__ part, float* __restrict__ part2) {
    const int g  = blockIdx.x / 6;           // group 0..31
    const int cb = blockIdx.x % 6;
    const int col = cb * 128 + threadIdx.x;
    float s = 0.f;
    #pragma unroll 8
    for (int p = g * 128; p < (g + 1) * 128; ++p) s += part[(size_t)p * HDIM + col];
    part2[g * HDIM + col] = s;
}

// ---------------- finalize stage 2: out[j] = sum_g src[g][j] / Z ----------------
__global__ __launch_bounds__(128) void fin2_kernel(
    const float* __restrict__ src, const float* __restrict__ Z,
    float* __restrict__ out, int ngroups) {
    const int col = blockIdx.x * 128 + threadIdx.x;
    float s = 0.f;
    for (int g = 0; g < ngroups; ++g) s += src[g * HDIM + col];
    out[col] = s / (*Z);
}

extern "C" void kernel_launch(void* const* d_in, const int* in_sizes, int n_in,
                              void* d_out, int out_size, void* d_ws, size_t ws_size,
                              hipStream_t stream) {
    const float* h    = (const float*)d_in[0];   // [N, 768]
    const float* W    = (const float*)d_in[1];   // [768, 768]
    const float* bias = (const float*)d_in[2];   // [768]
    const float* vv   = (const float*)d_in[3];   // [1, 768]
    float* out = (float*)d_out;                  // [1, 768] fp32

    const int n = in_sizes[0] / HDIM;            // 131072

    char* ws = (char*)d_ws;
    _Float16* Wt  = (_Float16*)(ws + WS_WT);
    float* Z      = (float*)(ws + WS_Z);
    float* part   = (float*)(ws + WS_PART);
    float* part2  = (float*)(ws + WS_PART2);
    float* accbuf = (float*)(ws + WS_PART);      // small-ws fallback accumulator

    const int use_part = (ws_size >= (size_t)WS_NEED) ? 1 : 0;

    hipFuncSetAttribute((const void*)score_fused_kernel,
                        hipFuncAttributeMaxDynamicSharedMemorySize, LDS_TOTAL);

    // 1) W -> fp16 chunks; zero Z (+acc)
    prep_kernel<<<72, 1024, 0, stream>>>(W, Wt, Z, accbuf);

    // 2) fused score + exp + weighted-sum partials
    score_fused_kernel<<<n / BM, 1024, LDS_TOTAL, stream>>>(
        h, Wt, bias, vv, part, accbuf, Z, use_part);

    // 3) reduce partials
    if (use_part) {
        fin1_kernel<<<192, 128, 0, stream>>>(part, part2);
        fin2_kernel<<<HDIM / 128, 128, 0, stream>>>(part2, Z, out, 32);
    } else {
        fin2_kernel<<<HDIM / 128, 128, 0, stream>>>(accbuf, Z, out, 1);
    }
}

// Round 19
// 278.513 us; speedup vs baseline: 1.3024x; 1.3024x over previous
//
#include <hip/hip_runtime.h>

#define HDIM 768
#define BM 64                 // rows per block
#define NC64 12               // K chunks of 64
#define CHALF 24576           // halves per 32k Wt sub-chunk (768 cols * 32 k)
#define A_STRIDE 1552         // bytes per A row in LDS (768*2 + 16 pad)

typedef _Float16 f16x8 __attribute__((ext_vector_type(8)));
typedef _Float16 f16x4 __attribute__((ext_vector_type(4)));
typedef _Float16 f16x2 __attribute__((ext_vector_type(2)));
typedef float f32x4 __attribute__((ext_vector_type(4)));

// ---- LDS layout (bytes), dynamic: 109824 (1 block/CU, 4 waves/SIMD => 128-reg budget) ----
#define LDS_A     0            // A resident: [64][1552B] = 99328
#define LDS_BIAS  99328        // 768 f32
#define LDS_V     102400       // 768 f32
#define LDS_SRED  105472       // [16][64] f32 = 4096
#define LDS_E     109568       // 64 f32
#define LDS_TOTAL 109824

// ---- workspace layout (bytes) ----
#define WS_WT    0             // 768*768*2 = 1179648 (fp16 W, chunked [kc32][col][32k], linear)
#define WS_Z     1179648       // 4 (+pad) [absorbs the benign tail B-prefetch OOB reads]
#define WS_PART  1179712       // 2048*768*4 = 6291456
#define WS_PART2 7471168       // 16*768*4 = 49152
#define WS_NEED  (WS_PART2 + 49152)

__device__ __forceinline__ float tanh_fast(float z) {
    float e2 = __expf(2.0f * z);
    return 1.0f - 2.0f / (e2 + 1.0f);   // inf-safe at both extremes
}

__device__ __forceinline__ f16x8 cvt8(f32x4 x0, f32x4 x1) {
    f16x8 f;
    f[0] = (_Float16)x0[0]; f[1] = (_Float16)x0[1];
    f[2] = (_Float16)x0[2]; f[3] = (_Float16)x0[3];
    f[4] = (_Float16)x1[0]; f[5] = (_Float16)x1[1];
    f[6] = (_Float16)x1[2]; f[7] = (_Float16)x1[3];
    return f;
}

// ---------------- kernel 1: W -> fp16 chunks [kc32][col][32k] (linear); zero Z + acc ----------------
__global__ __launch_bounds__(1024) void prep_kernel(
    const float* __restrict__ W, _Float16* __restrict__ Wt,
    float* __restrict__ Z, float* __restrict__ accbuf) {
    int idx = blockIdx.x * 1024 + threadIdx.x;      // 73728 groups: 768 c x 24 kc x 4 q
    if (idx < 73728) {
        int c  = idx / 96;
        int r  = idx - c * 96;
        int kc = r >> 2;
        int q  = r & 3;
        const float* src = W + c * HDIM + kc * 32 + q * 8;
        f16x8 v = cvt8(*(const f32x4*)src, *(const f32x4*)(src + 4));
        *(f16x8*)(Wt + (size_t)kc * CHALF + c * 32 + q * 8) = v;
    }
    if (idx < HDIM) accbuf[idx] = 0.0f;
    if (idx == 0) *Z = 0.0f;
}

// ---------------- kernel 2: fused GEMM + tanh + v-dot + exp + weighted sum ----------------
// r19 = r15 base with BK=64 FAT CHUNKS (NCHUNK 24->12). Rationale: r12-r18 establish a
// stable ~3450cy/chunk wall = sum-of-pipes (~2570) + ~900cy fixed per-chunk overhead
// (boundary/interlock), insensitive to barriers/occupancy/A-buffering. Halving the chunk
// count halves the overhead count (predicted -15%). Side effects: 1-deep B ping-pong at
// BK=64 = r15's 2-deep absolute latency slack; second half-chunk's A ds_reads issue
// under first half's MFMAs (r17's interleave, free). Absolute indices (r16 lesson).
__global__ __launch_bounds__(1024, 4) void score_fused_kernel(
    const float* __restrict__ h, const _Float16* __restrict__ Wt,
    const float* __restrict__ bias, const float* __restrict__ vvec,
    float* __restrict__ part, float* __restrict__ accbuf,
    float* __restrict__ Z, int use_part) {

    extern __shared__ char smem[];
    float* bias_s = (float*)(smem + LDS_BIAS);
    float* v_s    = (float*)(smem + LDS_V);
    float* s_red  = (float*)(smem + LDS_SRED);
    float* e_lds  = (float*)(smem + LDS_E);

    const int tid  = threadIdx.x;
    const int wave = tid >> 6;       // = col-group 0..15 (48 cols each)
    const int lane = tid & 63;
    const int l15  = lane & 15;
    const int lhi  = lane >> 4;
    const int row0 = blockIdx.x * BM;

    if (tid < HDIM) { bias_s[tid] = bias[tid]; v_s[tid] = vvec[tid]; }

    // ---- prologue: stage ENTIRE A tile (64 x 768 fp32 -> fp16), coalesced ----
    #pragma unroll
    for (int i = 0; i < 12; ++i) {
        int flat = i * 1024 + tid;          // 0..12287 = 64 rows x 192 f32x4
        int r  = flat / 192;
        int c4 = flat - r * 192;
        f32x4 x = __builtin_nontemporal_load(
            (const f32x4*)(h + (size_t)(row0 + r) * HDIM + c4 * 4));
        f16x4 v;
        v[0] = (_Float16)x[0]; v[1] = (_Float16)x[1];
        v[2] = (_Float16)x[2]; v[3] = (_Float16)x[3];
        *(f16x4*)(smem + LDS_A + r * A_STRIDE + c4 * 8) = v;
    }

    // B prefetch: ping set = 64k-chunk 0 (sub-chunks 0,1)
    const _Float16* wtp = Wt + (wave * 48 + l15) * 32 + lhi * 8;
    f16x8 pA0 = *(const f16x8*)(wtp);
    f16x8 pA1 = *(const f16x8*)(wtp + 512);
    f16x8 pA2 = *(const f16x8*)(wtp + 1024);
    f16x8 pA3 = *(const f16x8*)(wtp + CHALF);
    f16x8 pA4 = *(const f16x8*)(wtp + CHALF + 512);
    f16x8 pA5 = *(const f16x8*)(wtp + CHALF + 1024);
    f16x8 pB0, pB1, pB2, pB3, pB4, pB5;

    __syncthreads();   // the only pre-epilogue barrier: A tile + bias/v visible

    f32x4 acc[4][3];
    #pragma unroll
    for (int rt = 0; rt < 4; ++rt)
        #pragma unroll
        for (int ct = 0; ct < 3; ++ct)
            acc[rt][ct] = (f32x4){0.f, 0.f, 0.f, 0.f};

    const char* aBase = smem + LDS_A + l15 * A_STRIDE + lhi * 16;

// compute 64k-chunk KC (ABSOLUTE index; pointers never advance) from set C0..C5;
// prefetch 64k-chunk KC+1 (6 loads) into N0..N5. A offsets are imm.
// Tail: KC=11 prefetches sub-chunks 24,25 -> up to 96KB past Wt into Z/part (mapped,
// loaded-but-never-consumed).
#define CHUNK64(KC, C0, C1, C2, C3, C4, C5, N0, N1, N2, N3, N4, N5)                      \
    {                                                                                    \
        const _Float16* wn = wtp + (size_t)(2 * (KC) + 2) * CHALF;                       \
        N0 = *(const f16x8*)(wn);                                                        \
        N1 = *(const f16x8*)(wn + 512);                                                  \
        N2 = *(const f16x8*)(wn + 1024);                                                 \
        N3 = *(const f16x8*)(wn + CHALF);                                                \
        N4 = *(const f16x8*)(wn + CHALF + 512);                                          \
        N5 = *(const f16x8*)(wn + CHALF + 1024);                                         \
        const char* ab0 = aBase + (2 * (KC)) * 64;                                       \
        f16x8 a0 = *(const f16x8*)(ab0);                                                 \
        f16x8 a1 = *(const f16x8*)(ab0 + 16 * A_STRIDE);                                 \
        f16x8 a2 = *(const f16x8*)(ab0 + 32 * A_STRIDE);                                 \
        f16x8 a3 = *(const f16x8*)(ab0 + 48 * A_STRIDE);                                 \
        __builtin_amdgcn_s_setprio(1);                                                   \
        acc[0][0] = __builtin_amdgcn_mfma_f32_16x16x32_f16(a0, C0, acc[0][0], 0, 0, 0);  \
        acc[0][1] = __builtin_amdgcn_mfma_f32_16x16x32_f16(a0, C1, acc[0][1], 0, 0, 0);  \
        acc[0][2] = __builtin_amdgcn_mfma_f32_16x16x32_f16(a0, C2, acc[0][2], 0, 0, 0);  \
        acc[1][0] = __builtin_amdgcn_mfma_f32_16x16x32_f16(a1, C0, acc[1][0], 0, 0, 0);  \
        acc[1][1] = __builtin_amdgcn_mfma_f32_16x16x32_f16(a1, C1, acc[1][1], 0, 0, 0);  \
        acc[1][2] = __builtin_amdgcn_mfma_f32_16x16x32_f16(a1, C2, acc[1][2], 0, 0, 0);  \
        acc[2][0] = __builtin_amdgcn_mfma_f32_16x16x32_f16(a2, C0, acc[2][0], 0, 0, 0);  \
        acc[2][1] = __builtin_amdgcn_mfma_f32_16x16x32_f16(a2, C1, acc[2][1], 0, 0, 0);  \
        acc[2][2] = __builtin_amdgcn_mfma_f32_16x16x32_f16(a2, C2, acc[2][2], 0, 0, 0);  \
        acc[3][0] = __builtin_amdgcn_mfma_f32_16x16x32_f16(a3, C0, acc[3][0], 0, 0, 0);  \
        acc[3][1] = __builtin_amdgcn_mfma_f32_16x16x32_f16(a3, C1, acc[3][1], 0, 0, 0);  \
        acc[3][2] = __builtin_amdgcn_mfma_f32_16x16x32_f16(a3, C2, acc[3][2], 0, 0, 0);  \
        __builtin_amdgcn_s_setprio(0);                                                   \
        const char* ab1 = ab0 + 64;                                                      \
        f16x8 b0 = *(const f16x8*)(ab1);                                                 \
        f16x8 b1 = *(const f16x8*)(ab1 + 16 * A_STRIDE);                                 \
        f16x8 b2 = *(const f16x8*)(ab1 + 32 * A_STRIDE);                                 \
        f16x8 b3 = *(const f16x8*)(ab1 + 48 * A_STRIDE);                                 \
        __builtin_amdgcn_s_setprio(1);                                                   \
        acc[0][0] = __builtin_amdgcn_mfma_f32_16x16x32_f16(b0, C3, acc[0][0], 0, 0, 0);  \
        acc[0][1] = __builtin_amdgcn_mfma_f32_16x16x32_f16(b0, C4, acc[0][1], 0, 0, 0);  \
        acc[0][2] = __builtin_amdgcn_mfma_f32_16x16x32_f16(b0, C5, acc[0][2], 0, 0, 0);  \
        acc[1][0] = __builtin_amdgcn_mfma_f32_16x16x32_f16(b1, C3, acc[1][0], 0, 0, 0);  \
        acc[1][1] = __builtin_amdgcn_mfma_f32_16x16x32_f16(b1, C4, acc[1][1], 0, 0, 0);  \
        acc[1][2] = __builtin_amdgcn_mfma_f32_16x16x32_f16(b1, C5, acc[1][2], 0, 0, 0);  \
        acc[2][0] = __builtin_amdgcn_mfma_f32_16x16x32_f16(b2, C3, acc[2][0], 0, 0, 0);  \
        acc[2][1] = __builtin_amdgcn_mfma_f32_16x16x32_f16(b2, C4, acc[2][1], 0, 0, 0);  \
        acc[2][2] = __builtin_amdgcn_mfma_f32_16x16x32_f16(b2, C5, acc[2][2], 0, 0, 0);  \
        acc[3][0] = __builtin_amdgcn_mfma_f32_16x16x32_f16(b3, C3, acc[3][0], 0, 0, 0);  \
        acc[3][1] = __builtin_amdgcn_mfma_f32_16x16x32_f16(b3, C4, acc[3][1], 0, 0, 0);  \
        acc[3][2] = __builtin_amdgcn_mfma_f32_16x16x32_f16(b3, C5, acc[3][2], 0, 0, 0);  \
        __builtin_amdgcn_s_setprio(0);                                                   \
    }

    #pragma unroll 1
    for (int k2 = 0; k2 < NC64; k2 += 2) {
        CHUNK64(k2,     pA0, pA1, pA2, pA3, pA4, pA5, pB0, pB1, pB2, pB3, pB4, pB5)
        CHUNK64(k2 + 1, pB0, pB1, pB2, pB3, pB4, pB5, pA0, pA1, pA2, pA3, pA4, pA5)
    }
#undef CHUNK64

    // ---- epilogue: per-wave col-partial scores ----
    float pr[4][4];
    #pragma unroll
    for (int rt = 0; rt < 4; ++rt)
        #pragma unroll
        for (int r = 0; r < 4; ++r) pr[rt][r] = 0.f;

    #pragma unroll
    for (int ct = 0; ct < 3; ++ct) {
        int col = wave * 48 + ct * 16 + l15;
        float bj = bias_s[col];
        float vj = v_s[col];
        #pragma unroll
        for (int rt = 0; rt < 4; ++rt)
            #pragma unroll
            for (int r = 0; r < 4; ++r)
                pr[rt][r] = fmaf(vj, tanh_fast(acc[rt][ct][r] + bj), pr[rt][r]);
    }
    #pragma unroll
    for (int rt = 0; rt < 4; ++rt)
        #pragma unroll
        for (int r = 0; r < 4; ++r) {
            float x = pr[rt][r];
            x += __shfl_xor(x, 1);
            x += __shfl_xor(x, 2);
            x += __shfl_xor(x, 4);
            x += __shfl_xor(x, 8);
            if (l15 == 0) s_red[wave * 64 + rt * 16 + lhi * 4 + r] = x;
        }
    __syncthreads();

    // rows: sum 16 col-group partials, exp, block Z
    if (tid < 64) {
        float s = 0.f;
        #pragma unroll
        for (int w = 0; w < 16; ++w) s += s_red[w * 64 + tid];
        float e = __expf(s);            // |s| <= ||v||_1 ~ 61: no overflow
        e_lds[tid] = e;
        float tot = e;
        tot += __shfl_xor(tot, 1);
        tot += __shfl_xor(tot, 2);
        tot += __shfl_xor(tot, 4);
        tot += __shfl_xor(tot, 8);
        tot += __shfl_xor(tot, 16);
        tot += __shfl_xor(tot, 32);
        if (tid == 0) atomicAdd(Z, tot);
    }
    __syncthreads();

    // ---- fused weighted sum from resident A (h read from HBM exactly once), f16x2/lane ----
    if (tid < 384) {
        float s0 = 0.f, s1 = 0.f;
        #pragma unroll 8
        for (int i = 0; i < BM; ++i) {
            f16x2 a2 = *(const f16x2*)(smem + LDS_A + i * A_STRIDE + tid * 4);
            float e = e_lds[i];
            s0 = fmaf(e, (float)a2[0], s0);
            s1 = fmaf(e, (float)a2[1], s1);
        }
        if (use_part) {
            float* dst = part + (size_t)blockIdx.x * HDIM + tid * 2;
            dst[0] = s0; dst[1] = s1;
        } else {
            atomicAdd(accbuf + tid * 2, s0);
            atomicAdd(accbuf + tid * 2 + 1, s1);
        }
    }
}

// ---------------- finalize stage 1: sum 2048 parts in 16 groups of 128 ----------------
__global__ __launch_bounds__(128) void fin1_kernel(
    const float* __restrict__ part, float* __restrict__ part2) {
    const int g  = blockIdx.x / 6;           // group 0..15
    const int cb = blockIdx.x % 6;
    const int col = cb * 128 + threadIdx.x;
    float s = 0.f;
    #pragma unroll 8
    for (int p = g * 128; p < (g + 1) * 128; ++p) s += part[(size_t)p * HDIM + col];
    part2[g * HDIM + col] = s;
}

// ---------------- finalize stage 2: out[j] = sum_g src[g][j] / Z ----------------
__global__ __launch_bounds__(128) void fin2_kernel(
    const float* __restrict__ src, const float* __restrict__ Z,
    float* __restrict__ out, int ngroups) {
    const int col = blockIdx.x * 128 + threadIdx.x;
    float s = 0.f;
    for (int g = 0; g < ngroups; ++g) s += src[g * HDIM + col];
    out[col] = s / (*Z);
}

extern "C" void kernel_launch(void* const* d_in, const int* in_sizes, int n_in,
                              void* d_out, int out_size, void* d_ws, size_t ws_size,
                              hipStream_t stream) {
    const float* h    = (const float*)d_in[0];   // [N, 768]
    const float* W    = (const float*)d_in[1];   // [768, 768]
    const float* bias = (const float*)d_in[2];   // [768]
    const float* vv   = (const float*)d_in[3];   // [1, 768]
    float* out = (float*)d_out;                  // [1, 768] fp32

    const int n = in_sizes[0] / HDIM;            // 131072

    char* ws = (char*)d_ws;
    _Float16* Wt  = (_Float16*)(ws + WS_WT);
    float* Z      = (float*)(ws + WS_Z);
    float* part   = (float*)(ws + WS_PART);
    float* part2  = (float*)(ws + WS_PART2);
    float* accbuf = (float*)(ws + WS_PART);      // small-ws fallback accumulator

    const int use_part = (ws_size >= (size_t)WS_NEED) ? 1 : 0;

    hipFuncSetAttribute((const void*)score_fused_kernel,
                        hipFuncAttributeMaxDynamicSharedMemorySize, LDS_TOTAL);

    // 1) W -> fp16 chunks; zero Z (+acc)
    prep_kernel<<<72, 1024, 0, stream>>>(W, Wt, Z, accbuf);

    // 2) fused score + exp + weighted-sum partials
    score_fused_kernel<<<n / BM, 1024, LDS_TOTAL, stream>>>(
        h, Wt, bias, vv, part, accbuf, Z, use_part);

    // 3) reduce partials
    if (use_part) {
        fin1_kernel<<<96, 128, 0, stream>>>(part, part2);
        fin2_kernel<<<HDIM / 128, 128, 0, stream>>>(part2, Z, out, 16);
    } else {
        fin2_kernel<<<HDIM / 128, 128, 0, stream>>>(accbuf, Z, out, 1);
    }
}